// Round 4
// baseline (348.380 us; speedup 1.0000x reference)
//
#include <hip/hip_runtime.h>
#include <stdint.h>

#define S_LEN 4096
#define HDIM  2048
#define NHEAD 16
#define HD    128
#define WIN   1024

typedef float  f32x4  __attribute__((ext_vector_type(4)));
typedef float  f32x4v __attribute__((ext_vector_type(4)));
typedef __bf16 bf16x8 __attribute__((ext_vector_type(8)));
typedef short  short8 __attribute__((ext_vector_type(8)));
typedef short  short4v __attribute__((ext_vector_type(4)));

static __device__ __forceinline__ short f2bf(float f) {
  union { float f; uint32_t u; } v; v.f = f;
  uint32_t r = (v.u + 0x7FFFu + ((v.u >> 16) & 1u)) >> 16;
  return (short)(uint16_t)r;
}

static __device__ __forceinline__ void gload_lds16(const void* g, void* l) {
  __builtin_amdgcn_global_load_lds((__attribute__((address_space(1))) void*)g,
                                   (__attribute__((address_space(3))) void*)l,
                                   16, 0, 0);
}

// ---------------- RMSNorm: f32 x (4096x2048) -> bf16 xn ----------------
__global__ __launch_bounds__(256) void rmsnorm_k(const float* __restrict__ x,
                                                 const float* __restrict__ w,
                                                 short* __restrict__ xn) {
  const int row = blockIdx.x;
  const int t = threadIdx.x;
  const float* xr = x + (size_t)row * HDIM;
  f32x4v a = *(const f32x4v*)&xr[t * 8];
  f32x4v b = *(const f32x4v*)&xr[t * 8 + 4];
  float ss = a.x*a.x + a.y*a.y + a.z*a.z + a.w*a.w
           + b.x*b.x + b.y*b.y + b.z*b.z + b.w*b.w;
#pragma unroll
  for (int d = 1; d < 64; d <<= 1) ss += __shfl_xor(ss, d, 64);
  __shared__ float sred[4];
  if ((t & 63) == 0) sred[t >> 6] = ss;
  __syncthreads();
  float tot = sred[0] + sred[1] + sred[2] + sred[3];
  float rs = rsqrtf(tot * (1.0f / HDIM) + 1e-5f);
  float vv[8] = {a.x, a.y, a.z, a.w, b.x, b.y, b.z, b.w};
  const float* wp = w + t * 8;
  short8 o;
#pragma unroll
  for (int j = 0; j < 8; ++j) o[j] = f2bf(vv[j] * rs * wp[j]);
  *(short8*)&xn[(size_t)row * HDIM + t * 8] = o;
}

// ---------------- f32 -> bf16 weight convert ----------------
__global__ __launch_bounds__(256) void cvt_k(const float* __restrict__ in,
                                             short* __restrict__ out, int n4) {
  int i = blockIdx.x * 256 + threadIdx.x;
  if (i >= n4) return;
  f32x4v v = *(const f32x4v*)&in[(size_t)i * 4];
  short4v o = { f2bf(v.x), f2bf(v.y), f2bf(v.z), f2bf(v.w) };
  *(short4v*)&out[(size_t)i * 4] = o;
}

// ---------------- pipelined 256x256 bf16 GEMM, B^T input ----------------
// 8 waves (2M x 4N), per-wave 128x64 output. K-slot = 32, 4-slot LDS ring
// (128 KB). Per slot: one barrier + one counted vmcnt(8); stages for slot
// t+3 issued after the iter-t barrier (slot t-1 reads lgkm-drained before
// each wave's iter-(t-1) MFMA, hence before this barrier -> no clobber).
// T2 swizzle: 16B-slot index ^= (row>>1)&3 on both stage-source and read.
template <int EPI>
__global__ __launch_bounds__(512, 2) void gemm_p2(
    const short* __restrict__ A, const short* __restrict__ Bt,
    int M, int N, int K, float* __restrict__ Cf,
    const float* __restrict__ cosb, const float* __restrict__ sinb,
    short* __restrict__ Qo, short* __restrict__ Ko, short* __restrict__ Vt) {
  // slot: A 256x32 (8192 shorts) | B 256x32 (8192 shorts)
  __shared__ __align__(16) short lds[4][16384];
  const int t = threadIdx.x;
  const int w = t >> 6, l = t & 63;
  const int lr = l & 15, lg = l >> 4;
  const int wm = w >> 2, wn = w & 3;

  int bid = blockIdx.x;
  const int nwg = gridDim.x;
  bid = (bid & 7) * (nwg >> 3) + (bid >> 3);   // bijective XCD remap (nwg%8==0)
  const int nby = M >> 8;
  const int by = bid % nby, bx = bid / nby;    // by fastest: XCD chunk shares B-panels
  const int brow = by * 256, bcol = bx * 256;

  const int srow_l = l >> 2;                             // row within 16-row group
  const int scol = (((l & 3) ^ ((l >> 3) & 3)) * 8);     // inverse-swizzled src col (shorts)

  f32x4 acc[8][4] = {};
  const int nt = K >> 5;

#define STAGE_A(s, kt, j)                                                      \
  gload_lds16(A + (size_t)(brow + (j) * 128 + w * 16 + srow_l) * K + (kt) + scol, \
              &lds[s][(j) * 4096 + w * 512])
#define STAGE_B(s, kt, j)                                                      \
  gload_lds16(Bt + (size_t)(bcol + (j) * 128 + w * 16 + srow_l) * K + (kt) + scol, \
              &lds[s][8192 + (j) * 4096 + w * 512])
#define STAGE(s, kt) do { STAGE_A(s, kt, 0); STAGE_A(s, kt, 1);                \
                          STAGE_B(s, kt, 0); STAGE_B(s, kt, 1); } while (0)

  // prologue: stage slots 0,1,2 (12 loads in flight)
  STAGE(0, 0); STAGE(1, 32); STAGE(2, 64);

  const int xoff = ((lg ^ ((lr >> 1) & 3)) << 4);        // read swizzle (bytes)
  const int arow = (wm * 128 + lr) * 64;                 // byte base (row part)
  const int brow_b = 16384 + (wn * 64 + lr) * 64;

  for (int tt = 0; tt < nt; ++tt) {
    if (tt < nt - 2)       asm volatile("s_waitcnt vmcnt(8)" ::: "memory");
    else if (tt == nt - 2) asm volatile("s_waitcnt vmcnt(4)" ::: "memory");
    else                   asm volatile("s_waitcnt vmcnt(0)" ::: "memory");
    __builtin_amdgcn_s_barrier();
    __builtin_amdgcn_sched_barrier(0);
    const int slot = tt & 3;
    if (tt + 3 < nt) STAGE((tt + 3) & 3, (tt + 3) << 5);

    const char* sb = (const char*)&lds[slot][0];
    bf16x8 af[8], bfr[4];
#pragma unroll
    for (int m = 0; m < 8; ++m)
      af[m] = *(const bf16x8*)(sb + arow + m * 1024 + xoff);
#pragma unroll
    for (int n = 0; n < 4; ++n)
      bfr[n] = *(const bf16x8*)(sb + brow_b + n * 1024 + xoff);
    __builtin_amdgcn_s_setprio(1);
#pragma unroll
    for (int m = 0; m < 8; ++m)
#pragma unroll
      for (int n = 0; n < 4; ++n)
        acc[m][n] = __builtin_amdgcn_mfma_f32_16x16x32_bf16(af[m], bfr[n], acc[m][n], 0, 0, 0);
    __builtin_amdgcn_s_setprio(0);
  }
#undef STAGE
#undef STAGE_A
#undef STAGE_B

  const int row0 = brow + wm * 128, col0 = bcol + wn * 64;
  if (EPI == 0) {
#pragma unroll
    for (int m = 0; m < 8; ++m)
#pragma unroll
      for (int n = 0; n < 4; ++n)
#pragma unroll
        for (int r = 0; r < 4; ++r)
          Cf[(size_t)(row0 + m * 16 + lg * 4 + r) * N + col0 + n * 16 + lr] = acc[m][n][r];
  } else {
    const int sec = col0 >> 11;                 // uniform per wave (sections 2048-aligned)
    const int headc = (col0 & 2047) >> 7;       // uniform per wave (64-wide within head)
    const bool rope = (sec < 2) && ((col0 & 127) == 0);
#pragma unroll
    for (int m = 0; m < 8; ++m) {
#pragma unroll
      for (int r = 0; r < 4; ++r) {
        const int s = row0 + m * 16 + lg * 4 + r;
        float v0 = acc[m][0][r], v1 = acc[m][1][r];
        float v2 = acc[m][2][r], v3 = acc[m][3][r];
        if (rope) {
          const int d0 = lr;
          float c0 = cosb[s * 32 + d0],      sn0 = sinb[s * 32 + d0];
          float c1 = cosb[s * 32 + d0 + 16], sn1 = sinb[s * 32 + d0 + 16];
          float t0 = v0 * c0 - v1 * sn0;
          float t1 = v1 * c1 + v0 * sn1;
          v0 = t0; v1 = t1;
        }
        float vv[4] = {v0, v1, v2, v3};
#pragma unroll
        for (int n = 0; n < 4; ++n) {
          const int col = col0 + n * 16 + lr;
          const int d = col & 127;
          if (sec == 0)
            Qo[((size_t)headc * S_LEN + s) * HD + d] = f2bf(vv[n] * 0.08838834764831845f);
          else if (sec == 1)
            Ko[((size_t)headc * S_LEN + s) * HD + d] = f2bf(vv[n]);
          else
            Vt[((size_t)headc * HD + d) * S_LEN + s] = f2bf(vv[n]);
        }
      }
    }
  }
}

// ---------------- sliding-window flash attention ----------------
__global__ __launch_bounds__(256) void attn_k(const short* __restrict__ Q,
                                              const short* __restrict__ Kk,
                                              const short* __restrict__ Vt,
                                              short* __restrict__ Ao) {
  __shared__ __align__(16) short Kl[64 * HD];
  __shared__ __align__(16) short Vl[HD * 64];
  __shared__ __align__(16) short Pl[4][16 * 72];
  const int head = blockIdx.y;
  int bxx = blockIdx.x;
  bxx = ((bxx & 7) << 3) | (bxx >> 3);
  const int qb = bxx * 64;
  const int w = threadIdx.x >> 6, l = threadIdx.x & 63;
  const int lr = l & 15, lg = l >> 4;
  const int q0w = qb + w * 16;
  const short* Qh = Q  + (size_t)head * S_LEN * HD;
  const short* Kh = Kk + (size_t)head * S_LEN * HD;
  const short* Vh = Vt + (size_t)head * HD * S_LEN;

  bf16x8 qf[4];
#pragma unroll
  for (int kk = 0; kk < 4; ++kk)
    qf[kk] = *(const bf16x8*)&Qh[(size_t)(q0w + lr) * HD + kk * 32 + lg * 8];

  f32x4 oacc[8] = {};
  float mrow[4], lrow[4];
#pragma unroll
  for (int r = 0; r < 4; ++r) { mrow[r] = -1e30f; lrow[r] = 0.0f; }

  const int k_begin = (qb >= WIN) ? (qb - WIN) : 0;
  const int nt = (qb + 64 - k_begin) >> 6;
  const int swz = (lr & 7) << 4;

  for (int tkv = 0; tkv < nt; ++tkv) {
    const int k0 = k_begin + tkv * 64;
#pragma unroll
    for (int i = 0; i < 4; ++i) {
      const int row = i * 16 + w * 4 + (l >> 4);
      gload_lds16(Kh + (size_t)(k0 + row) * HD + (((l & 15) ^ (row & 7)) * 8),
                  &Kl[(i * 16 + w * 4) * HD]);
    }
#pragma unroll
    for (int i = 0; i < 4; ++i) {
      const int row = i * 32 + w * 8 + (l >> 3);
      gload_lds16(Vh + (size_t)row * S_LEN + k0 + (((l & 7) ^ (row & 7)) * 8),
                  &Vl[(i * 32 + w * 8) * 64]);
    }
    __syncthreads();

    f32x4 sacc[4] = {};
#pragma unroll
    for (int nf = 0; nf < 4; ++nf) {
      const char* kb = (const char*)Kl + (nf * 16 + lr) * 256;
      bf16x8 kf[4];
#pragma unroll
      for (int kk = 0; kk < 4; ++kk)
        kf[kk] = *(const bf16x8*)(kb + ((kk * 64 + lg * 16) ^ swz));
#pragma unroll
      for (int kk = 0; kk < 4; ++kk)
        sacc[nf] = __builtin_amdgcn_mfma_f32_16x16x32_bf16(qf[kk], kf[kk], sacc[nf], 0, 0, 0);
    }

    const bool full = (k0 + 63 <= q0w) && (k0 >= q0w + 15 - WIN);
    float scl[4];
#pragma unroll
    for (int r = 0; r < 4; ++r) {
      const int i = q0w + lg * 4 + r;
      float sv[4];
#pragma unroll
      for (int nf = 0; nf < 4; ++nf) sv[nf] = sacc[nf][r];
      if (!full) {
#pragma unroll
        for (int nf = 0; nf < 4; ++nf) {
          const int j = k0 + nf * 16 + lr;
          if (!((j <= i) && (j + WIN >= i))) sv[nf] = -1e30f;
        }
      }
      float mx = fmaxf(fmaxf(sv[0], sv[1]), fmaxf(sv[2], sv[3]));
#pragma unroll
      for (int d = 1; d < 16; d <<= 1) mx = fmaxf(mx, __shfl_xor(mx, d, 64));
      const float mn = fmaxf(mrow[r], mx);
      const float sc = __expf(mrow[r] - mn);
      mrow[r] = mn;
      float p[4], rs = 0.0f;
#pragma unroll
      for (int nf = 0; nf < 4; ++nf) { p[nf] = __expf(sv[nf] - mn); rs += p[nf]; }
#pragma unroll
      for (int d = 1; d < 16; d <<= 1) rs += __shfl_xor(rs, d, 64);
      lrow[r] = lrow[r] * sc + rs;
      scl[r] = sc;
#pragma unroll
      for (int nf = 0; nf < 4; ++nf)
        Pl[w][(lg * 4 + r) * 72 + nf * 16 + lr] = f2bf(p[nf]);
    }
#pragma unroll
    for (int df = 0; df < 8; ++df)
#pragma unroll
      for (int r = 0; r < 4; ++r) oacc[df][r] *= scl[r];

    bf16x8 pa[2];
#pragma unroll
    for (int kk2 = 0; kk2 < 2; ++kk2)
      pa[kk2] = *(const bf16x8*)&Pl[w][lr * 72 + kk2 * 32 + lg * 8];

#pragma unroll
    for (int df = 0; df < 8; ++df) {
      const char* vb = (const char*)Vl + (df * 16 + lr) * 128;
#pragma unroll
      for (int kk2 = 0; kk2 < 2; ++kk2) {
        bf16x8 vfrag = *(const bf16x8*)(vb + ((kk2 * 64 + lg * 16) ^ swz));
        oacc[df] = __builtin_amdgcn_mfma_f32_16x16x32_bf16(pa[kk2], vfrag, oacc[df], 0, 0, 0);
      }
    }
    __syncthreads();
  }

  float inv[4];
#pragma unroll
  for (int r = 0; r < 4; ++r) inv[r] = 1.0f / lrow[r];
#pragma unroll
  for (int df = 0; df < 8; ++df)
#pragma unroll
    for (int r = 0; r < 4; ++r) {
      const int s = q0w + lg * 4 + r;
      Ao[(size_t)s * HDIM + head * HD + df * 16 + lr] = f2bf(oacc[df][r] * inv[r]);
    }
}

extern "C" void kernel_launch(void* const* d_in, const int* in_sizes, int n_in,
                              void* d_out, int out_size, void* d_ws, size_t ws_size,
                              hipStream_t stream) {
  const float* x    = (const float*)d_in[0];
  const float* cosb = (const float*)d_in[1];
  const float* sinb = (const float*)d_in[2];
  const float* nw   = (const float*)d_in[3];
  const float* qkvw = (const float*)d_in[4];
  const float* ow   = (const float*)d_in[5];
  float* out = (float*)d_out;

  short* ws = (short*)d_ws;
  short* xn = ws;
  short* wb = xn + (size_t)S_LEN * HDIM;
  short* Qb = wb + (size_t)3 * HDIM * HDIM;
  short* Kb = Qb + (size_t)NHEAD * S_LEN * HD;
  short* Vb = Kb + (size_t)NHEAD * S_LEN * HD;
  short* Ao = xn;

  rmsnorm_k<<<S_LEN, 256, 0, stream>>>(x, nw, xn);
  cvt_k<<<(3 * HDIM * HDIM / 4 + 255) / 256, 256, 0, stream>>>(qkvw, wb, 3 * HDIM * HDIM / 4);
  gemm_p2<1><<<(3 * HDIM / 256) * (S_LEN / 256), 512, 0, stream>>>(
      xn, wb, S_LEN, 3 * HDIM, HDIM, nullptr, cosb, sinb, Qb, Kb, Vb);
  cvt_k<<<(HDIM * HDIM / 4 + 255) / 256, 256, 0, stream>>>(ow, wb, HDIM * HDIM / 4);
  attn_k<<<dim3(S_LEN / 64, NHEAD), 256, 0, stream>>>(Qb, Kb, Vb, Ao);
  gemm_p2<0><<<(HDIM / 256) * (S_LEN / 256), 512, 0, stream>>>(
      Ao, wb, S_LEN, HDIM, HDIM, out, nullptr, nullptr, nullptr, nullptr, nullptr);
}

// Round 5
// 318.673 us; speedup vs baseline: 1.0932x; 1.0932x over previous
//
#include <hip/hip_runtime.h>
#include <stdint.h>

#define S_LEN 4096
#define HDIM  2048
#define NHEAD 16
#define HD    128
#define WIN   1024

typedef float  f32x4  __attribute__((ext_vector_type(4)));
typedef float  f32x4v __attribute__((ext_vector_type(4)));
typedef __bf16 bf16x8 __attribute__((ext_vector_type(8)));
typedef short  short8 __attribute__((ext_vector_type(8)));
typedef short  short4v __attribute__((ext_vector_type(4)));

static __device__ __forceinline__ short f2bf(float f) {
  union { float f; uint32_t u; } v; v.f = f;
  uint32_t r = (v.u + 0x7FFFu + ((v.u >> 16) & 1u)) >> 16;
  return (short)(uint16_t)r;
}

static __device__ __forceinline__ void gload_lds16(const void* g, void* l) {
  __builtin_amdgcn_global_load_lds((__attribute__((address_space(1))) void*)g,
                                   (__attribute__((address_space(3))) void*)l,
                                   16, 0, 0);
}

// ---------------- RMSNorm: f32 x (4096x2048) -> bf16 xn ----------------
__global__ __launch_bounds__(256) void rmsnorm_k(const float* __restrict__ x,
                                                 const float* __restrict__ w,
                                                 short* __restrict__ xn) {
  const int row = blockIdx.x;
  const int t = threadIdx.x;
  const float* xr = x + (size_t)row * HDIM;
  f32x4v a = *(const f32x4v*)&xr[t * 8];
  f32x4v b = *(const f32x4v*)&xr[t * 8 + 4];
  float ss = a.x*a.x + a.y*a.y + a.z*a.z + a.w*a.w
           + b.x*b.x + b.y*b.y + b.z*b.z + b.w*b.w;
#pragma unroll
  for (int d = 1; d < 64; d <<= 1) ss += __shfl_xor(ss, d, 64);
  __shared__ float sred[4];
  if ((t & 63) == 0) sred[t >> 6] = ss;
  __syncthreads();
  float tot = sred[0] + sred[1] + sred[2] + sred[3];
  float rs = rsqrtf(tot * (1.0f / HDIM) + 1e-5f);
  float vv[8] = {a.x, a.y, a.z, a.w, b.x, b.y, b.z, b.w};
  const float* wp = w + t * 8;
  short8 o;
#pragma unroll
  for (int j = 0; j < 8; ++j) o[j] = f2bf(vv[j] * rs * wp[j]);
  *(short8*)&xn[(size_t)row * HDIM + t * 8] = o;
}

// ---------------- f32 -> bf16 weight convert ----------------
__global__ __launch_bounds__(256) void cvt_k(const float* __restrict__ in,
                                             short* __restrict__ out, int n4) {
  int i = blockIdx.x * 256 + threadIdx.x;
  if (i >= n4) return;
  f32x4v v = *(const f32x4v*)&in[(size_t)i * 4];
  short4v o = { f2bf(v.x), f2bf(v.y), f2bf(v.z), f2bf(v.w) };
  *(short4v*)&out[(size_t)i * 4] = o;
}

// ---------------- pipelined 256x128 bf16 GEMM, B^T input ----------------
// 8 waves (4M x 2N), per-wave 64x64 output. Pipeline quantum = (dbuf,kh)
// column-group (BK=32 cols of a BK=64 K-tile). 4-group ring over 2 K-tiles.
// Each phase: vmcnt(6) -> barrier -> stage 3 sweeps (serves phase p+3; its
// region was read at phase p-3, drained by this barrier) -> 8 ds_read ->
// 16 MFMA. One barrier per phase; no explicit lgkm drain (compiler partial
// lgkmcnt lets trailing reads overlap leading MFMAs).
// LDS plane layout [kh][row][32 shorts]; stage dest linear (t*16B);
// source col-slot pre-permuted with f(row)=(row+(row>>2))&3; read uses the
// same XOR -> min-aliasing (conflict-free) ds_read_b128.

template <int D, int KH>
__device__ __forceinline__ void ph_compute(const short* ldsb, f32x4 (&acc)[4][4],
                                           int aro, int bro) {
  const short* pl = ldsb + D * 24576;
  bf16x8 af[4], bfr[4];
#pragma unroll
  for (int m = 0; m < 4; ++m)
    af[m] = *(const bf16x8*)&pl[KH * 8192 + aro + m * 512];
#pragma unroll
  for (int n = 0; n < 4; ++n)
    bfr[n] = *(const bf16x8*)&pl[16384 + KH * 4096 + bro + n * 512];
  __builtin_amdgcn_s_setprio(1);
#pragma unroll
  for (int m = 0; m < 4; ++m)
#pragma unroll
    for (int n = 0; n < 4; ++n)
      acc[m][n] = __builtin_amdgcn_mfma_f32_16x16x32_bf16(af[m], bfr[n], acc[m][n], 0, 0, 0);
  __builtin_amdgcn_s_setprio(0);
}

template <int EPI>
__global__ __launch_bounds__(512, 2) void gemm_p3(
    const short* __restrict__ A, const short* __restrict__ Bt,
    int M, int N, int K, float* __restrict__ Cf,
    const float* __restrict__ cosb, const float* __restrict__ sinb,
    short* __restrict__ Qo, short* __restrict__ Ko, short* __restrict__ Vt) {
  __shared__ __align__(16) short lds[2][24576];   // 96 KB
  const int t = threadIdx.x;
  const int w = t >> 6, l = t & 63;
  const int lr = l & 15, lg = l >> 4;
  const int wm = w >> 1, wn = w & 1;

  int bid = blockIdx.x;
  const int nwg = gridDim.x;
  bid = (bid & 7) * (nwg >> 3) + (bid >> 3);   // bijective XCD remap (nwg%8==0)
  const int nby = M >> 8;
  const int by = bid % nby, bx = bid / nby;    // by fastest: share B-panel in L2
  const int brow = by * 256, bcol = bx * 128;

  // staging: thread t covers row (t>>2) of a 128-row sweep, 16B slot (t&3)
  const int srow = t >> 2;
  const int sg = (t & 3) ^ ((srow + (srow >> 2)) & 3);   // inverse-permuted src slot
  const short* As0 = A  + (size_t)(brow + srow) * K + sg * 8;
  const short* As1 = A  + (size_t)(brow + 128 + srow) * K + sg * 8;
  const short* Bs  = Bt + (size_t)(bcol + srow) * K + sg * 8;

  // read offsets (shorts, within dbuf plane)
  const int fr = (lr + (lr >> 2)) & 3;
  const int aro = (wm * 64 + lr) * 32 + ((lg ^ fr) * 8);
  const int bro = (wn * 64 + lr) * 32 + ((lg ^ fr) * 8);

  f32x4 acc[4][4] = {};
  const int nt = K >> 6;            // BK=64 K-tiles; nt even, >= 4
  const short* ldsb = &lds[0][0];

#define STG(SD, U, SKH) do {                                             \
    const size_t ko = (size_t)((U) * 64 + (SKH) * 32);                   \
    gload_lds16(As0 + ko, &lds[SD][(SKH) * 8192 + t * 8]);               \
    gload_lds16(As1 + ko, &lds[SD][(SKH) * 8192 + 4096 + t * 8]);        \
    gload_lds16(Bs  + ko, &lds[SD][16384 + (SKH) * 4096 + t * 8]);       \
  } while (0)

#define PHASE(D, KH, VM, DOSTG, SD, SU, SKH)                             \
  asm volatile("s_waitcnt vmcnt(" #VM ")" ::: "memory");                 \
  __builtin_amdgcn_s_barrier();                                          \
  __builtin_amdgcn_sched_barrier(0);                                     \
  if (DOSTG) { STG(SD, SU, SKH); }                                       \
  ph_compute<D, KH>(ldsb, acc, aro, bro);

  // prologue: stage groups for phases 0,1,2
  STG(0, 0, 0); STG(0, 0, 1); STG(1, 1, 0);

  for (int u = 0; u < nt - 2; u += 2) {
    PHASE(0, 0, 6, true, 1, u + 1, 1)      // (u,kh0)   stages (u+1).kh1
    PHASE(0, 1, 6, true, 0, u + 2, 0)      // (u,kh1)   stages (u+2).kh0
    PHASE(1, 0, 6, true, 0, u + 2, 1)      // (u+1,kh0) stages (u+2).kh1
    PHASE(1, 1, 6, true, 1, u + 3, 0)      // (u+1,kh1) stages (u+3).kh0
  }
  // peeled tail: u = nt-2 (d=0), nt-1 (d=1)
  PHASE(0, 0, 6, true, 1, nt - 1, 1)       // stages last group (nt-1).kh1
  PHASE(0, 1, 6, false, 0, 0, 0)
  PHASE(1, 0, 3, false, 0, 0, 0)
  PHASE(1, 1, 0, false, 0, 0, 0)
#undef PHASE
#undef STG

  const int row0 = brow + wm * 64, col0 = bcol + wn * 64;
  if (EPI == 0) {
#pragma unroll
    for (int m = 0; m < 4; ++m)
#pragma unroll
      for (int n = 0; n < 4; ++n)
#pragma unroll
        for (int r = 0; r < 4; ++r)
          Cf[(size_t)(row0 + m * 16 + lg * 4 + r) * N + col0 + n * 16 + lr] = acc[m][n][r];
  } else {
    const int sec = col0 >> 11;                 // uniform per wave
    const int headc = (col0 & 2047) >> 7;
    const bool rope = (sec < 2) && ((col0 & 127) == 0);
#pragma unroll
    for (int m = 0; m < 4; ++m) {
#pragma unroll
      for (int r = 0; r < 4; ++r) {
        const int s = row0 + m * 16 + lg * 4 + r;
        float v0 = acc[m][0][r], v1 = acc[m][1][r];
        float v2 = acc[m][2][r], v3 = acc[m][3][r];
        if (rope) {
          const int d0 = lr;
          float c0 = cosb[s * 32 + d0],      sn0 = sinb[s * 32 + d0];
          float c1 = cosb[s * 32 + d0 + 16], sn1 = sinb[s * 32 + d0 + 16];
          float t0 = v0 * c0 - v1 * sn0;
          float t1 = v1 * c1 + v0 * sn1;
          v0 = t0; v1 = t1;
        }
        float vv[4] = {v0, v1, v2, v3};
#pragma unroll
        for (int n = 0; n < 4; ++n) {
          const int col = col0 + n * 16 + lr;
          const int d = col & 127;
          if (sec == 0)
            Qo[((size_t)headc * S_LEN + s) * HD + d] = f2bf(vv[n] * 0.08838834764831845f);
          else if (sec == 1)
            Ko[((size_t)headc * S_LEN + s) * HD + d] = f2bf(vv[n]);
          else
            Vt[((size_t)headc * HD + d) * S_LEN + s] = f2bf(vv[n]);
        }
      }
    }
  }
}

// ---------------- sliding-window flash attention ----------------
__global__ __launch_bounds__(256) void attn_k(const short* __restrict__ Q,
                                              const short* __restrict__ Kk,
                                              const short* __restrict__ Vt,
                                              short* __restrict__ Ao) {
  __shared__ __align__(16) short Kl[64 * HD];
  __shared__ __align__(16) short Vl[HD * 64];
  __shared__ __align__(16) short Pl[4][16 * 72];
  const int head = blockIdx.y;
  int bxx = blockIdx.x;
  bxx = ((bxx & 7) << 3) | (bxx >> 3);
  const int qb = bxx * 64;
  const int w = threadIdx.x >> 6, l = threadIdx.x & 63;
  const int lr = l & 15, lg = l >> 4;
  const int q0w = qb + w * 16;
  const short* Qh = Q  + (size_t)head * S_LEN * HD;
  const short* Kh = Kk + (size_t)head * S_LEN * HD;
  const short* Vh = Vt + (size_t)head * HD * S_LEN;

  bf16x8 qf[4];
#pragma unroll
  for (int kk = 0; kk < 4; ++kk)
    qf[kk] = *(const bf16x8*)&Qh[(size_t)(q0w + lr) * HD + kk * 32 + lg * 8];

  f32x4 oacc[8] = {};
  float mrow[4], lrow[4];
#pragma unroll
  for (int r = 0; r < 4; ++r) { mrow[r] = -1e30f; lrow[r] = 0.0f; }

  const int k_begin = (qb >= WIN) ? (qb - WIN) : 0;
  const int nt = (qb + 64 - k_begin) >> 6;
  const int swz = (lr & 7) << 4;

  for (int tkv = 0; tkv < nt; ++tkv) {
    const int k0 = k_begin + tkv * 64;
#pragma unroll
    for (int i = 0; i < 4; ++i) {
      const int row = i * 16 + w * 4 + (l >> 4);
      gload_lds16(Kh + (size_t)(k0 + row) * HD + (((l & 15) ^ (row & 7)) * 8),
                  &Kl[(i * 16 + w * 4) * HD]);
    }
#pragma unroll
    for (int i = 0; i < 4; ++i) {
      const int row = i * 32 + w * 8 + (l >> 3);
      gload_lds16(Vh + (size_t)row * S_LEN + k0 + (((l & 7) ^ (row & 7)) * 8),
                  &Vl[(i * 32 + w * 8) * 64]);
    }
    __syncthreads();

    f32x4 sacc[4] = {};
#pragma unroll
    for (int nf = 0; nf < 4; ++nf) {
      const char* kb = (const char*)Kl + (nf * 16 + lr) * 256;
      bf16x8 kf[4];
#pragma unroll
      for (int kk = 0; kk < 4; ++kk)
        kf[kk] = *(const bf16x8*)(kb + ((kk * 64 + lg * 16) ^ swz));
#pragma unroll
      for (int kk = 0; kk < 4; ++kk)
        sacc[nf] = __builtin_amdgcn_mfma_f32_16x16x32_bf16(qf[kk], kf[kk], sacc[nf], 0, 0, 0);
    }

    const bool full = (k0 + 63 <= q0w) && (k0 >= q0w + 15 - WIN);
    float scl[4];
#pragma unroll
    for (int r = 0; r < 4; ++r) {
      const int i = q0w + lg * 4 + r;
      float sv[4];
#pragma unroll
      for (int nf = 0; nf < 4; ++nf) sv[nf] = sacc[nf][r];
      if (!full) {
#pragma unroll
        for (int nf = 0; nf < 4; ++nf) {
          const int j = k0 + nf * 16 + lr;
          if (!((j <= i) && (j + WIN >= i))) sv[nf] = -1e30f;
        }
      }
      float mx = fmaxf(fmaxf(sv[0], sv[1]), fmaxf(sv[2], sv[3]));
#pragma unroll
      for (int d = 1; d < 16; d <<= 1) mx = fmaxf(mx, __shfl_xor(mx, d, 64));
      const float mn = fmaxf(mrow[r], mx);
      const float sc = __expf(mrow[r] - mn);
      mrow[r] = mn;
      float p[4], rs = 0.0f;
#pragma unroll
      for (int nf = 0; nf < 4; ++nf) { p[nf] = __expf(sv[nf] - mn); rs += p[nf]; }
#pragma unroll
      for (int d = 1; d < 16; d <<= 1) rs += __shfl_xor(rs, d, 64);
      lrow[r] = lrow[r] * sc + rs;
      scl[r] = sc;
#pragma unroll
      for (int nf = 0; nf < 4; ++nf)
        Pl[w][(lg * 4 + r) * 72 + nf * 16 + lr] = f2bf(p[nf]);
    }
#pragma unroll
    for (int df = 0; df < 8; ++df)
#pragma unroll
      for (int r = 0; r < 4; ++r) oacc[df][r] *= scl[r];

    bf16x8 pa[2];
#pragma unroll
    for (int kk2 = 0; kk2 < 2; ++kk2)
      pa[kk2] = *(const bf16x8*)&Pl[w][lr * 72 + kk2 * 32 + lg * 8];

#pragma unroll
    for (int df = 0; df < 8; ++df) {
      const char* vb = (const char*)Vl + (df * 16 + lr) * 128;
#pragma unroll
      for (int kk2 = 0; kk2 < 2; ++kk2) {
        bf16x8 vfrag = *(const bf16x8*)(vb + ((kk2 * 64 + lg * 16) ^ swz));
        oacc[df] = __builtin_amdgcn_mfma_f32_16x16x32_bf16(pa[kk2], vfrag, oacc[df], 0, 0, 0);
      }
    }
    __syncthreads();
  }

  float inv[4];
#pragma unroll
  for (int r = 0; r < 4; ++r) inv[r] = 1.0f / lrow[r];
#pragma unroll
  for (int df = 0; df < 8; ++df)
#pragma unroll
    for (int r = 0; r < 4; ++r) {
      const int s = q0w + lg * 4 + r;
      Ao[(size_t)s * HDIM + head * HD + df * 16 + lr] = f2bf(oacc[df][r] * inv[r]);
    }
}

extern "C" void kernel_launch(void* const* d_in, const int* in_sizes, int n_in,
                              void* d_out, int out_size, void* d_ws, size_t ws_size,
                              hipStream_t stream) {
  const float* x    = (const float*)d_in[0];
  const float* cosb = (const float*)d_in[1];
  const float* sinb = (const float*)d_in[2];
  const float* nw   = (const float*)d_in[3];
  const float* qkvw = (const float*)d_in[4];
  const float* ow   = (const float*)d_in[5];
  float* out = (float*)d_out;

  short* ws = (short*)d_ws;
  short* xn = ws;
  short* wb = xn + (size_t)S_LEN * HDIM;
  short* Qb = wb + (size_t)3 * HDIM * HDIM;
  short* Kb = Qb + (size_t)NHEAD * S_LEN * HD;
  short* Vb = Kb + (size_t)NHEAD * S_LEN * HD;
  short* Ao = xn;

  rmsnorm_k<<<S_LEN, 256, 0, stream>>>(x, nw, xn);
  cvt_k<<<(3 * HDIM * HDIM / 4 + 255) / 256, 256, 0, stream>>>(qkvw, wb, 3 * HDIM * HDIM / 4);
  gemm_p3<1><<<(S_LEN / 256) * (3 * HDIM / 128), 512, 0, stream>>>(
      xn, wb, S_LEN, 3 * HDIM, HDIM, nullptr, cosb, sinb, Qb, Kb, Vb);
  cvt_k<<<(HDIM * HDIM / 4 + 255) / 256, 256, 0, stream>>>(ow, wb, HDIM * HDIM / 4);
  attn_k<<<dim3(S_LEN / 64, NHEAD), 256, 0, stream>>>(Qb, Kb, Vb, Ao);
  gemm_p3<0><<<(S_LEN / 256) * (HDIM / 128), 512, 0, stream>>>(
      Ao, wb, S_LEN, HDIM, HDIM, out, nullptr, nullptr, nullptr, nullptr, nullptr);
}